// Round 4
// baseline (101.802 us; speedup 1.0000x reference)
//
#include <hip/hip_runtime.h>

// Reference:
//   num_trues = sum(evict_mask, axis=1); num_false = 128 - num_trues
//   start = floordiv(seq_len + num_false - 1, page) * page - seq_len
//   end   = min(start + page, 128); start_c = max(start, 0)
//   out[t] = (t >= start_c && t < end) ? 0 : evict_mask[t]
//
// B = 524288, D = 128. One 32-lane group per row (wave64 = 2 rows).
// bool in/out stored as int32 0/1 (proven round 1).
// Row-sum via 4x __ballot + popcount of the wave half (round 2: −9%).
// Round 3: 2-row unroll for MLP, pow2 fast path for the floor division,
// 2048-block grid (32 rows/thread).

typedef int vint4 __attribute__((ext_vector_type(4)));

__device__ __forceinline__ void process_row(
    vint4 v, int sl, int page, int lgp, int lane32, unsigned half_shift,
    int* __restrict__ out, size_t row)
{
    unsigned long long b0 = __ballot(v.x != 0);
    unsigned long long b1 = __ballot(v.y != 0);
    unsigned long long b2 = __ballot(v.z != 0);
    unsigned long long b3 = __ballot(v.w != 0);
    int cnt = __popc((unsigned)(b0 >> half_shift))
            + __popc((unsigned)(b1 >> half_shift))
            + __popc((unsigned)(b2 >> half_shift))
            + __popc((unsigned)(b3 >> half_shift));   // num_trues of MY row

    int s = sl + (128 - cnt) - 1;
    int q;
    if (lgp >= 0) {
        q = s >> lgp;                    // arithmetic shift == floor div (pow2)
    } else {
        q = s / page;                    // general floor division
        if (s < 0 && (s % page) != 0) q--;
    }
    int start = q * page - sl;
    int sc  = start > 0 ? start : 0;
    int end = start + page;
    if (end > 128) end = 128;

    int t0 = lane32 * 4;
    vint4 o;
    o.x = (t0 + 0 >= sc && t0 + 0 < end) ? 0 : ((v.x != 0) ? 1 : 0);
    o.y = (t0 + 1 >= sc && t0 + 1 < end) ? 0 : ((v.y != 0) ? 1 : 0);
    o.z = (t0 + 2 >= sc && t0 + 2 < end) ? 0 : ((v.z != 0) ? 1 : 0);
    o.w = (t0 + 3 >= sc && t0 + 3 < end) ? 0 : ((v.w != 0) ? 1 : 0);
    __builtin_nontemporal_store(o, reinterpret_cast<vint4*>(out) + row * 32 + lane32);
}

__global__ __launch_bounds__(256) void evict_range_kernel(
    const int* __restrict__ seq_lens,
    const int* __restrict__ evict_mask,
    const int* __restrict__ page_size_p,
    int* __restrict__ out,
    int batch)
{
    const int page = *page_size_p;                 // uniform scalar
    const int lgp = ((page & (page - 1)) == 0) ? (31 - __clz(page)) : -1;
    const int lane32 = threadIdx.x & 31;
    const unsigned half_shift = threadIdx.x & 32;
    const int tid = blockIdx.x * blockDim.x + threadIdx.x;
    const int group = tid >> 5;
    const int stride = (gridDim.x * blockDim.x) >> 5;

    const vint4* mbase = reinterpret_cast<const vint4*>(evict_mask);

    int row = group;
    // unrolled-by-2 main loop: both loads in flight before any consumption
    for (; row + stride < batch; row += 2 * stride) {
        int rowB = row + stride;
        vint4 vA = __builtin_nontemporal_load(mbase + (size_t)row  * 32 + lane32);
        vint4 vB = __builtin_nontemporal_load(mbase + (size_t)rowB * 32 + lane32);
        int slA = seq_lens[row];
        int slB = seq_lens[rowB];
        process_row(vA, slA, page, lgp, lane32, half_shift, out, (size_t)row);
        process_row(vB, slB, page, lgp, lane32, half_shift, out, (size_t)rowB);
    }
    if (row < batch) {
        vint4 vA = __builtin_nontemporal_load(mbase + (size_t)row * 32 + lane32);
        int slA = seq_lens[row];
        process_row(vA, slA, page, lgp, lane32, half_shift, out, (size_t)row);
    }
}

extern "C" void kernel_launch(void* const* d_in, const int* in_sizes, int n_in,
                              void* d_out, int out_size, void* d_ws, size_t ws_size,
                              hipStream_t stream) {
    const int* seq_lens   = (const int*)d_in[0];
    const int* evict_mask = (const int*)d_in[1];
    const int* page_size  = (const int*)d_in[2];
    int* out = (int*)d_out;
    const int batch = in_sizes[0];

    // 2048 blocks x 256 threads -> 16384 row-groups, 32 rows/thread (16 unrolled iters)
    const int blocks = 2048;
    evict_range_kernel<<<blocks, 256, 0, stream>>>(seq_lens, evict_mask, page_size, out, batch);
}

// Round 5
// 98.286 us; speedup vs baseline: 1.0358x; 1.0358x over previous
//
#include <hip/hip_runtime.h>

// Reference:
//   num_trues = sum(evict_mask, axis=1); num_false = 128 - num_trues
//   start = floordiv(seq_len + num_false - 1, page) * page - seq_len
//   end   = min(start + page, 128); start_c = max(start, 0)
//   out[t] = (t >= start_c && t < end) ? 0 : evict_mask[t]
//
// B = 524288, D = 128. One 32-lane group per row (wave64 = 2 rows).
// bool in/out stored as int32 0/1 (proven round 1).
// Row-sum via 4x __ballot + popcount of the wave half (round 2: 103->94.6).
// Round 3 regression isolated to the 8192->2048 grid cut (scheduler tail);
// round 4 reverts grid to 8192, keeps 2-row unroll + pow2 shift.

typedef int vint4 __attribute__((ext_vector_type(4)));

__device__ __forceinline__ void process_row(
    vint4 v, int sl, int page, int lgp, int lane32, unsigned half_shift,
    int* __restrict__ out, size_t row)
{
    unsigned long long b0 = __ballot(v.x != 0);
    unsigned long long b1 = __ballot(v.y != 0);
    unsigned long long b2 = __ballot(v.z != 0);
    unsigned long long b3 = __ballot(v.w != 0);
    int cnt = __popc((unsigned)(b0 >> half_shift))
            + __popc((unsigned)(b1 >> half_shift))
            + __popc((unsigned)(b2 >> half_shift))
            + __popc((unsigned)(b3 >> half_shift));   // num_trues of MY row

    int s = sl + (128 - cnt) - 1;
    int q;
    if (lgp >= 0) {
        q = s >> lgp;                    // arithmetic shift == floor div (pow2)
    } else {
        q = s / page;                    // general floor division
        if (s < 0 && (s % page) != 0) q--;
    }
    int start = q * page - sl;
    int sc  = start > 0 ? start : 0;
    int end = start + page;
    if (end > 128) end = 128;

    int t0 = lane32 * 4;
    vint4 o;
    o.x = (t0 + 0 >= sc && t0 + 0 < end) ? 0 : ((v.x != 0) ? 1 : 0);
    o.y = (t0 + 1 >= sc && t0 + 1 < end) ? 0 : ((v.y != 0) ? 1 : 0);
    o.z = (t0 + 2 >= sc && t0 + 2 < end) ? 0 : ((v.z != 0) ? 1 : 0);
    o.w = (t0 + 3 >= sc && t0 + 3 < end) ? 0 : ((v.w != 0) ? 1 : 0);
    __builtin_nontemporal_store(o, reinterpret_cast<vint4*>(out) + row * 32 + lane32);
}

__global__ __launch_bounds__(256) void evict_range_kernel(
    const int* __restrict__ seq_lens,
    const int* __restrict__ evict_mask,
    const int* __restrict__ page_size_p,
    int* __restrict__ out,
    int batch)
{
    const int page = *page_size_p;                 // uniform scalar
    const int lgp = ((page & (page - 1)) == 0) ? (31 - __clz(page)) : -1;
    const int lane32 = threadIdx.x & 31;
    const unsigned half_shift = threadIdx.x & 32;
    const int tid = blockIdx.x * blockDim.x + threadIdx.x;
    const int group = tid >> 5;
    const int stride = (gridDim.x * blockDim.x) >> 5;

    const vint4* mbase = reinterpret_cast<const vint4*>(evict_mask);

    int row = group;
    // unrolled-by-2 main loop: both loads in flight before any consumption
    for (; row + stride < batch; row += 2 * stride) {
        int rowB = row + stride;
        vint4 vA = __builtin_nontemporal_load(mbase + (size_t)row  * 32 + lane32);
        vint4 vB = __builtin_nontemporal_load(mbase + (size_t)rowB * 32 + lane32);
        int slA = seq_lens[row];
        int slB = seq_lens[rowB];
        process_row(vA, slA, page, lgp, lane32, half_shift, out, (size_t)row);
        process_row(vB, slB, page, lgp, lane32, half_shift, out, (size_t)rowB);
    }
    if (row < batch) {
        vint4 vA = __builtin_nontemporal_load(mbase + (size_t)row * 32 + lane32);
        int slA = seq_lens[row];
        process_row(vA, slA, page, lgp, lane32, half_shift, out, (size_t)row);
    }
}

extern "C" void kernel_launch(void* const* d_in, const int* in_sizes, int n_in,
                              void* d_out, int out_size, void* d_ws, size_t ws_size,
                              hipStream_t stream) {
    const int* seq_lens   = (const int*)d_in[0];
    const int* evict_mask = (const int*)d_in[1];
    const int* page_size  = (const int*)d_in[2];
    int* out = (int*)d_out;
    const int batch = in_sizes[0];

    // 8192 blocks x 256 threads -> 65536 row-groups, 8 rows/thread (4 unrolled iters)
    const int blocks = 8192;
    evict_range_kernel<<<blocks, 256, 0, stream>>>(seq_lens, evict_mask, page_size, out, batch);
}

// Round 6
// 85.525 us; speedup vs baseline: 1.1903x; 1.1492x over previous
//
#include <hip/hip_runtime.h>

// Reference:
//   num_trues = sum(evict_mask, axis=1); num_false = 128 - num_trues
//   start = floordiv(seq_len + num_false - 1, page) * page - seq_len
//   end   = min(start + page, 128); start_c = max(start, 0)
//   out[t] = (t >= start_c && t < end) ? 0 : evict_mask[t]
//
// B = 524288, D = 128. One 32-lane group per row (wave64 = 2 rows).
// bool in/out stored as int32 0/1 (proven round 1).
// History: shuffle 103.5 -> ballot 94.6 (r2) -> grid cut 101.8 (r3, bad)
//          -> unroll@8192 98.3 (r4, bad). Best = r2 form.
// Round 5: no grid-stride loop at all -- exactly one group per row,
// 65536 blocks. Load -> ballot -> store -> retire (fill-kernel pattern).

typedef int vint4 __attribute__((ext_vector_type(4)));

__global__ __launch_bounds__(256) void evict_range_kernel(
    const int* __restrict__ seq_lens,
    const int* __restrict__ evict_mask,
    const int* __restrict__ page_size_p,
    int* __restrict__ out,
    int batch)
{
    const int page = *page_size_p;                 // uniform scalar
    const int lgp = ((page & (page - 1)) == 0) ? (31 - __clz(page)) : -1;
    const int lane32 = threadIdx.x & 31;
    const unsigned half_shift = threadIdx.x & 32;
    const int row = blockIdx.x * 8 + (threadIdx.x >> 5);   // one group == one row
    if (row >= batch) return;

    const vint4* mrow = reinterpret_cast<const vint4*>(evict_mask) + (size_t)row * 32;
    vint4 v = __builtin_nontemporal_load(&mrow[lane32]);

    // wave-wide ballots: low 32 bits = rows of lanes 0-31, high = lanes 32-63
    unsigned long long b0 = __ballot(v.x != 0);
    unsigned long long b1 = __ballot(v.y != 0);
    unsigned long long b2 = __ballot(v.z != 0);
    unsigned long long b3 = __ballot(v.w != 0);
    int cnt = __popc((unsigned)(b0 >> half_shift))
            + __popc((unsigned)(b1 >> half_shift))
            + __popc((unsigned)(b2 >> half_shift))
            + __popc((unsigned)(b3 >> half_shift));   // num_trues of MY row

    int sl = seq_lens[row];
    int s = sl + (128 - cnt) - 1;
    int q;
    if (lgp >= 0) {
        q = s >> lgp;                    // arithmetic shift == floor div (pow2)
    } else {
        q = s / page;                    // general floor division
        if (s < 0 && (s % page) != 0) q--;
    }
    int start = q * page - sl;
    int sc  = start > 0 ? start : 0;
    int end = start + page;
    if (end > 128) end = 128;

    int t0 = lane32 * 4;
    vint4 o;
    o.x = (t0 + 0 >= sc && t0 + 0 < end) ? 0 : ((v.x != 0) ? 1 : 0);
    o.y = (t0 + 1 >= sc && t0 + 1 < end) ? 0 : ((v.y != 0) ? 1 : 0);
    o.z = (t0 + 2 >= sc && t0 + 2 < end) ? 0 : ((v.z != 0) ? 1 : 0);
    o.w = (t0 + 3 >= sc && t0 + 3 < end) ? 0 : ((v.w != 0) ? 1 : 0);
    __builtin_nontemporal_store(o, reinterpret_cast<vint4*>(out) + (size_t)row * 32 + lane32);
}

extern "C" void kernel_launch(void* const* d_in, const int* in_sizes, int n_in,
                              void* d_out, int out_size, void* d_ws, size_t ws_size,
                              hipStream_t stream) {
    const int* seq_lens   = (const int*)d_in[0];
    const int* evict_mask = (const int*)d_in[1];
    const int* page_size  = (const int*)d_in[2];
    int* out = (int*)d_out;
    const int batch = in_sizes[0];

    // one 32-lane group per row: 524288 groups = 65536 blocks x 256 threads
    const int blocks = (batch + 7) / 8;
    evict_range_kernel<<<blocks, 256, 0, stream>>>(seq_lens, evict_mask, page_size, out, batch);
}